// Round 1
// baseline (423.200 us; speedup 1.0000x reference)
//
#include <hip/hip_runtime.h>
#include <hip/hip_bf16.h>

// Problem constants (reference file): N_SRC=200000, N_DST=50000, N_EDGES=800000,
// IN_FEATS=128, OUT_FEATS=64.

#define IN_F   128
#define OUT_F  64

// ---------------------------------------------------------------------------
// K1: h = x @ W   (rows x 128) @ (128 x 64), f32 vector ALU.
// Block = 256 threads = 4 waves. W staged in LDS (32 KB) once per block.
// Each wave computes 16 rows x 64 cols: lane = output column, 16 f32 accums.
// Per k: one stride-1 LDS read of W row (free bank pattern) reused by 16 FMAs;
// x reads are wave-uniform -> scalar loads.
// ---------------------------------------------------------------------------
__global__ __launch_bounds__(256) void gemm_xw(const float* __restrict__ x,
                                               const float* __restrict__ W,
                                               float* __restrict__ h,
                                               int n_rows) {
    __shared__ float Wl[IN_F * OUT_F];   // 32 KB

    const int tid = threadIdx.x;
    // Cooperative W load, vectorized (2048 float4s / 256 threads = 8 each).
    {
        const float4* Wv = reinterpret_cast<const float4*>(W);
        float4* Wlv = reinterpret_cast<float4*>(Wl);
        #pragma unroll
        for (int i = 0; i < (IN_F * OUT_F / 4) / 256; ++i)
            Wlv[tid + i * 256] = Wv[tid + i * 256];
    }
    __syncthreads();

    const int lane = tid & 63;
    const int waveInBlock = tid >> 6;                       // 0..3
    const long waveId = (long)blockIdx.x * 4 + waveInBlock; // global wave id
    const long row0 = waveId * 16;
    if (row0 >= n_rows) return;

    float acc[16];
    #pragma unroll
    for (int r = 0; r < 16; ++r) acc[r] = 0.0f;

    const float* xbase = x + row0 * IN_F;

    for (int k4 = 0; k4 < IN_F; k4 += 4) {
        float4 xs[16];
        #pragma unroll
        for (int r = 0; r < 16; ++r)
            xs[r] = *reinterpret_cast<const float4*>(&xbase[r * IN_F + k4]);
        #pragma unroll
        for (int kk = 0; kk < 4; ++kk) {
            const float wv = Wl[(k4 + kk) * OUT_F + lane];
            #pragma unroll
            for (int r = 0; r < 16; ++r) {
                const float xv = reinterpret_cast<const float*>(&xs[r])[kk];
                acc[r] = fmaf(xv, wv, acc[r]);
            }
        }
    }

    float* hbase = h + row0 * OUT_F;
    #pragma unroll
    for (int r = 0; r < 16; ++r)
        hbase[r * OUT_F + lane] = acc[r];
}

// ---------------------------------------------------------------------------
// K2: scatter-add. One wave per edge (grid-stride), lane = feature.
// out[dst][f] += h[src][f]  (f32 atomics, device scope);
// lane 0: deg[dst] += 1.0f
// ---------------------------------------------------------------------------
__global__ __launch_bounds__(256) void scatter_edges(const float* __restrict__ h,
                                                     const int* __restrict__ esrc,
                                                     const int* __restrict__ edst,
                                                     float* __restrict__ out,
                                                     float* __restrict__ deg,
                                                     int n_edges) {
    const int lane = threadIdx.x & 63;
    const int waveId = (blockIdx.x * blockDim.x + threadIdx.x) >> 6;
    const int nWaves = (gridDim.x * blockDim.x) >> 6;

    for (int e = waveId; e < n_edges; e += nWaves) {
        const int s = esrc[e];
        const int d = edst[e];
        const float v = h[(long)s * OUT_F + lane];
        atomicAdd(&out[(long)d * OUT_F + lane], v);
        if (lane == 0) atomicAdd(&deg[d], 1.0f);
    }
}

// ---------------------------------------------------------------------------
// K3: finalize. out[i] = (out[i] + h[i]) / (deg[i/64] + 1) + b[i%64]
// ---------------------------------------------------------------------------
__global__ __launch_bounds__(256) void finalize(float* __restrict__ out,
                                                const float* __restrict__ h,
                                                const float* __restrict__ deg,
                                                const float* __restrict__ b,
                                                int n_elems) {
    const int i = blockIdx.x * 256 + threadIdx.x;
    if (i >= n_elems) return;
    const int dst = i >> 6;
    const int f = i & 63;
    const float v = (out[i] + h[i]) / (deg[dst] + 1.0f) + b[f];
    out[i] = v;
}

extern "C" void kernel_launch(void* const* d_in, const int* in_sizes, int n_in,
                              void* d_out, int out_size, void* d_ws, size_t ws_size,
                              hipStream_t stream) {
    const float* x    = (const float*)d_in[0];
    const int*   esrc = (const int*)d_in[1];
    const int*   edst = (const int*)d_in[2];
    const float* W    = (const float*)d_in[3];
    const float* b    = (const float*)d_in[4];
    // d_in[5] is n_dst (scalar on device); sizes are fixed for this problem.

    const int n_rows  = in_sizes[0] / IN_F;   // 200000
    const int n_edges = in_sizes[1];          // 800000
    const int n_dst   = out_size / OUT_F;     // 50000

    float* h   = (float*)d_ws;                         // n_rows*64 f32 = 51.2 MB
    float* deg = (float*)((char*)d_ws + (size_t)n_rows * OUT_F * sizeof(float));
    float* out = (float*)d_out;

    // Zero the accumulation targets (graph-capture-safe).
    hipMemsetAsync(out, 0, (size_t)out_size * sizeof(float), stream);
    hipMemsetAsync(deg, 0, (size_t)n_dst * sizeof(float), stream);

    // K1: GEMM. 16 rows/wave, 4 waves/block -> 64 rows/block.
    {
        const int blocks = (n_rows + 63) / 64;   // 3125
        gemm_xw<<<blocks, 256, 0, stream>>>(x, W, h, n_rows);
    }

    // K2: scatter. Grid-stride, 4 edges per block-iteration.
    {
        const int blocks = 8192;
        scatter_edges<<<blocks, 256, 0, stream>>>(h, esrc, edst, out, deg, n_edges);
    }

    // K3: finalize.
    {
        const int n_elems = n_dst * OUT_F;       // 3.2M
        const int blocks = (n_elems + 255) / 256;
        finalize<<<blocks, 256, 0, stream>>>(out, h, deg, b, n_elems);
    }
}

// Round 2
// 286.821 us; speedup vs baseline: 1.4755x; 1.4755x over previous
//
#include <hip/hip_runtime.h>
#include <hip/hip_bf16.h>

#define IN_F   128
#define OUT_F  64

// ---------------------------------------------------------------------------
// K1: h = x @ W  (f32 vector ALU; no f32 MFMA on CDNA4).
// Persistent blocks: 512 blocks (2/CU), each grid-strides over 64-row tiles.
// LDS: W[128][64] (32 KB, loaded once) + x-tile [64][132] padded (33.8 KB).
// Per lane: 4x4 register tile; rows rg+8p (bank-clean with stride 132),
// cols cg*4. Per 4-k step: 8 ds_read_b128 + 64 FMAs -> FMA-bound.
// ---------------------------------------------------------------------------
#define XS_STRIDE 132

__global__ __launch_bounds__(256) void gemm_xw(const float* __restrict__ x,
                                               const float* __restrict__ W,
                                               float* __restrict__ h,
                                               int nTiles) {
    __shared__ float Wl[IN_F * OUT_F];      // 32 KB
    __shared__ float xs[64 * XS_STRIDE];    // 33.8 KB

    const int tid = threadIdx.x;

    // Load W once (coalesced float4: 2048 f4 / 256 thr = 8 each).
    {
        const float4* Wv = reinterpret_cast<const float4*>(W);
        float4* Wlv = reinterpret_cast<float4*>(Wl);
        #pragma unroll
        for (int i = 0; i < 8; ++i)
            Wlv[tid + i * 256] = Wv[tid + i * 256];
    }

    const int lane = tid & 63;
    const int wave = tid >> 6;              // 0..3
    const int wM = wave >> 1;               // 0..1 (row half)
    const int wN = wave & 1;                // 0..1 (col half)
    const int rg = lane >> 3;               // 0..7
    const int cg = lane & 7;                // 0..7
    const int rBase = wM * 32 + rg;         // lane rows: rBase + 8p, p=0..3
    const int c0 = wN * 32 + cg * 4;        // lane cols: c0..c0+3

    for (int tile = blockIdx.x; tile < nTiles; tile += gridDim.x) {
        const long row0 = (long)tile * 64;

        __syncthreads();   // xs safe to overwrite (also orders first W load)
        // Stage x tile: 64 rows x 128 f32, coalesced (row stride = 32 f4).
        {
            const float4* xrow = reinterpret_cast<const float4*>(x + row0 * IN_F);
            #pragma unroll
            for (int i = 0; i < 8; ++i) {
                const int j = tid + i * 256;        // 0..2047
                const int r = j >> 5;
                const int kq = j & 31;
                const float4 v = xrow[j];
                *reinterpret_cast<float4*>(&xs[r * XS_STRIDE + kq * 4]) = v;
            }
        }
        __syncthreads();

        float acc[4][4];
        #pragma unroll
        for (int p = 0; p < 4; ++p)
            #pragma unroll
            for (int c = 0; c < 4; ++c) acc[p][c] = 0.0f;

        #pragma unroll 2
        for (int k4 = 0; k4 < 32; ++k4) {
            float4 xv[4], wv[4];
            #pragma unroll
            for (int p = 0; p < 4; ++p)
                xv[p] = *reinterpret_cast<const float4*>(&xs[(rBase + 8 * p) * XS_STRIDE + k4 * 4]);
            #pragma unroll
            for (int q = 0; q < 4; ++q)
                wv[q] = *reinterpret_cast<const float4*>(&Wl[(k4 * 4 + q) * OUT_F + c0]);
            #pragma unroll
            for (int p = 0; p < 4; ++p) {
                const float* xp = reinterpret_cast<const float*>(&xv[p]);
                #pragma unroll
                for (int q = 0; q < 4; ++q) {
                    const float xk = xp[q];
                    const float* wq = reinterpret_cast<const float*>(&wv[q]);
                    #pragma unroll
                    for (int c = 0; c < 4; ++c)
                        acc[p][c] = fmaf(xk, wq[c], acc[p][c]);
                }
            }
        }

        // Store h tile (float4, coalesced-ish across the 32x32 wave tile).
        float* hb = h + (row0 + rBase) * OUT_F + c0;
        #pragma unroll
        for (int p = 0; p < 4; ++p) {
            float4 v;
            v.x = acc[p][0]; v.y = acc[p][1]; v.z = acc[p][2]; v.w = acc[p][3];
            *reinterpret_cast<float4*>(&hb[(size_t)(8 * p) * OUT_F]) = v;
        }
    }
}

// ---------------------------------------------------------------------------
// CSR build: count -> scan -> fill
// ---------------------------------------------------------------------------
__global__ __launch_bounds__(256) void count_edges(const int* __restrict__ edst,
                                                   int* __restrict__ counts,
                                                   int n_edges) {
    const int e = blockIdx.x * 256 + threadIdx.x;
    if (e < n_edges) atomicAdd(&counts[edst[e]], 1);
}

__global__ __launch_bounds__(1024) void scan_counts(const int* __restrict__ counts,
                                                    int* __restrict__ offsets,
                                                    int* __restrict__ cursor,
                                                    int n_dst) {
    __shared__ int part[1024];
    const int t = threadIdx.x;
    const int chunk = (n_dst + 1023) / 1024;
    const int lo = t * chunk;
    const int hi = min(lo + chunk, n_dst);

    int s = 0;
    for (int i = lo; i < hi; ++i) s += counts[i];
    part[t] = s;
    __syncthreads();

    // Inclusive Hillis-Steele scan over 1024 partials.
    for (int off = 1; off < 1024; off <<= 1) {
        const int v = (t >= off) ? part[t - off] : 0;
        __syncthreads();
        part[t] += v;
        __syncthreads();
    }

    int base = (t > 0) ? part[t - 1] : 0;
    for (int i = lo; i < hi; ++i) {
        offsets[i] = base;
        cursor[i] = base;
        base += counts[i];
    }
    if (lo < n_dst && hi == n_dst) offsets[n_dst] = base;
}

__global__ __launch_bounds__(256) void fill_edges(const int* __restrict__ esrc,
                                                  const int* __restrict__ edst,
                                                  int* __restrict__ cursor,
                                                  int* __restrict__ elist,
                                                  int n_edges) {
    const int e = blockIdx.x * 256 + threadIdx.x;
    if (e < n_edges) {
        const int d = edst[e];
        const int slot = atomicAdd(&cursor[d], 1);
        elist[slot] = esrc[e];
    }
}

// ---------------------------------------------------------------------------
// K5: gather + finalize. One wave per dst, lane = feature.
// out[d][f] = (sum_e h[src_e][f] + h[d][f]) / (deg+1) + b[f]
// h (51 MB) is L3-resident -> gathers served from Infinity Cache.
// ---------------------------------------------------------------------------
__global__ __launch_bounds__(256) void gather_finalize(const float* __restrict__ h,
                                                       const int* __restrict__ offsets,
                                                       const int* __restrict__ elist,
                                                       const float* __restrict__ b,
                                                       float* __restrict__ out,
                                                       int n_dst) {
    const int lane = threadIdx.x & 63;
    const int d = blockIdx.x * 4 + (threadIdx.x >> 6);
    if (d >= n_dst) return;

    const int e0 = offsets[d];
    const int e1 = offsets[d + 1];

    float acc = h[(size_t)d * OUT_F + lane];

    for (int base = e0; base < e1; base += 64) {
        const int cnt = min(64, e1 - base);
        const int sidx = (base + lane < e1) ? elist[base + lane] : 0;
        int j = 0;
        for (; j + 4 <= cnt; j += 4) {
            const int s0 = __shfl(sidx, j);
            const int s1 = __shfl(sidx, j + 1);
            const int s2 = __shfl(sidx, j + 2);
            const int s3 = __shfl(sidx, j + 3);
            const float v0 = h[(size_t)s0 * OUT_F + lane];
            const float v1 = h[(size_t)s1 * OUT_F + lane];
            const float v2 = h[(size_t)s2 * OUT_F + lane];
            const float v3 = h[(size_t)s3 * OUT_F + lane];
            acc += (v0 + v1) + (v2 + v3);
        }
        for (; j < cnt; ++j) {
            const int s = __shfl(sidx, j);
            acc += h[(size_t)s * OUT_F + lane];
        }
    }

    const float deg = (float)(e1 - e0);
    out[(size_t)d * OUT_F + lane] = acc / (deg + 1.0f) + b[lane];
}

// ---------------------------------------------------------------------------
// Fallback path (ws too small): round-1 atomic scatter + finalize.
// ---------------------------------------------------------------------------
__global__ __launch_bounds__(256) void scatter_edges(const float* __restrict__ h,
                                                     const int* __restrict__ esrc,
                                                     const int* __restrict__ edst,
                                                     float* __restrict__ out,
                                                     float* __restrict__ deg,
                                                     int n_edges) {
    const int lane = threadIdx.x & 63;
    const int waveId = (blockIdx.x * blockDim.x + threadIdx.x) >> 6;
    const int nWaves = (gridDim.x * blockDim.x) >> 6;
    for (int e = waveId; e < n_edges; e += nWaves) {
        const int s = esrc[e];
        const int d = edst[e];
        atomicAdd(&out[(long)d * OUT_F + lane], h[(long)s * OUT_F + lane]);
        if (lane == 0) atomicAdd(&deg[d], 1.0f);
    }
}

__global__ __launch_bounds__(256) void finalize(float* __restrict__ out,
                                                const float* __restrict__ h,
                                                const float* __restrict__ deg,
                                                const float* __restrict__ b,
                                                int n_elems) {
    const int i = blockIdx.x * 256 + threadIdx.x;
    if (i >= n_elems) return;
    out[i] = (out[i] + h[i]) / (deg[i >> 6] + 1.0f) + b[i & 63];
}

static inline size_t align256(size_t v) { return (v + 255) & ~(size_t)255; }

extern "C" void kernel_launch(void* const* d_in, const int* in_sizes, int n_in,
                              void* d_out, int out_size, void* d_ws, size_t ws_size,
                              hipStream_t stream) {
    const float* x    = (const float*)d_in[0];
    const int*   esrc = (const int*)d_in[1];
    const int*   edst = (const int*)d_in[2];
    const float* W    = (const float*)d_in[3];
    const float* b    = (const float*)d_in[4];

    const int n_rows  = in_sizes[0] / IN_F;   // 200000
    const int n_edges = in_sizes[1];          // 800000
    const int n_dst   = out_size / OUT_F;     // 50000
    float* out = (float*)d_out;

    // Workspace layout
    const size_t hBytes  = (size_t)n_rows * OUT_F * sizeof(float);   // 51.2 MB
    const size_t cntOff  = align256(hBytes);
    const size_t offOff  = align256(cntOff + (size_t)n_dst * 4);
    const size_t curOff  = align256(offOff + ((size_t)n_dst + 1) * 4);
    const size_t elOff   = align256(curOff + (size_t)n_dst * 4);
    const size_t needed  = elOff + (size_t)n_edges * 4;

    float* h = (float*)d_ws;

    // K1: GEMM (persistent, 2 blocks/CU).
    const int nTiles = n_rows / 64;           // 3125 (200000 % 64 == 0)
    gemm_xw<<<512, 256, 0, stream>>>(x, W, h, nTiles);

    if (ws_size >= needed) {
        int* counts  = (int*)((char*)d_ws + cntOff);
        int* offsets = (int*)((char*)d_ws + offOff);
        int* cursor  = (int*)((char*)d_ws + curOff);
        int* elist   = (int*)((char*)d_ws + elOff);

        hipMemsetAsync(counts, 0, (size_t)n_dst * 4, stream);

        const int eBlocks = (n_edges + 255) / 256;
        count_edges<<<eBlocks, 256, 0, stream>>>(edst, counts, n_edges);
        scan_counts<<<1, 1024, 0, stream>>>(counts, offsets, cursor, n_dst);
        fill_edges<<<eBlocks, 256, 0, stream>>>(esrc, edst, cursor, elist, n_edges);

        const int gBlocks = (n_dst + 3) / 4;
        gather_finalize<<<gBlocks, 256, 0, stream>>>(h, offsets, elist, b, out, n_dst);
    } else {
        // Fallback: atomic scatter (round-1 path).
        float* deg = (float*)((char*)d_ws + cntOff);
        hipMemsetAsync(out, 0, (size_t)out_size * sizeof(float), stream);
        hipMemsetAsync(deg, 0, (size_t)n_dst * sizeof(float), stream);
        scatter_edges<<<8192, 256, 0, stream>>>(h, esrc, edst, out, deg, n_edges);
        const int n_elems = n_dst * OUT_F;
        finalize<<<(n_elems + 255) / 256, 256, 0, stream>>>(out, h, deg, b, n_elems);
    }
}

// Round 3
// 187.839 us; speedup vs baseline: 2.2530x; 1.5270x over previous
//
#include <hip/hip_runtime.h>
#include <hip/hip_bf16.h>

#define IN_F   128
#define OUT_F  64

// ---------------------------------------------------------------------------
// K1: h = x @ W  (f32 vector ALU; no f32 MFMA on CDNA4).
// Persistent blocks: 512 blocks (2/CU), each grid-strides over 64-row tiles.
// LDS: W[128][64] (32 KB, loaded once) + x-tile [64][132] padded (33.8 KB).
// ---------------------------------------------------------------------------
#define XS_STRIDE 132

__global__ __launch_bounds__(256) void gemm_xw(const float* __restrict__ x,
                                               const float* __restrict__ W,
                                               float* __restrict__ h,
                                               int nTiles) {
    __shared__ float Wl[IN_F * OUT_F];      // 32 KB
    __shared__ float xs[64 * XS_STRIDE];    // 33.8 KB

    const int tid = threadIdx.x;

    {
        const float4* Wv = reinterpret_cast<const float4*>(W);
        float4* Wlv = reinterpret_cast<float4*>(Wl);
        #pragma unroll
        for (int i = 0; i < 8; ++i)
            Wlv[tid + i * 256] = Wv[tid + i * 256];
    }

    const int lane = tid & 63;
    const int wave = tid >> 6;
    const int wM = wave >> 1;
    const int wN = wave & 1;
    const int rg = lane >> 3;
    const int cg = lane & 7;
    const int rBase = wM * 32 + rg;
    const int c0 = wN * 32 + cg * 4;

    for (int tile = blockIdx.x; tile < nTiles; tile += gridDim.x) {
        const long row0 = (long)tile * 64;

        __syncthreads();
        {
            const float4* xrow = reinterpret_cast<const float4*>(x + row0 * IN_F);
            #pragma unroll
            for (int i = 0; i < 8; ++i) {
                const int j = tid + i * 256;
                const int r = j >> 5;
                const int kq = j & 31;
                const float4 v = xrow[j];
                *reinterpret_cast<float4*>(&xs[r * XS_STRIDE + kq * 4]) = v;
            }
        }
        __syncthreads();

        float acc[4][4];
        #pragma unroll
        for (int p = 0; p < 4; ++p)
            #pragma unroll
            for (int c = 0; c < 4; ++c) acc[p][c] = 0.0f;

        #pragma unroll 2
        for (int k4 = 0; k4 < 32; ++k4) {
            float4 xv[4], wv[4];
            #pragma unroll
            for (int p = 0; p < 4; ++p)
                xv[p] = *reinterpret_cast<const float4*>(&xs[(rBase + 8 * p) * XS_STRIDE + k4 * 4]);
            #pragma unroll
            for (int q = 0; q < 4; ++q)
                wv[q] = *reinterpret_cast<const float4*>(&Wl[(k4 * 4 + q) * OUT_F + c0]);
            #pragma unroll
            for (int p = 0; p < 4; ++p) {
                const float* xp = reinterpret_cast<const float*>(&xv[p]);
                #pragma unroll
                for (int q = 0; q < 4; ++q) {
                    const float xk = xp[q];
                    const float* wq = reinterpret_cast<const float*>(&wv[q]);
                    #pragma unroll
                    for (int c = 0; c < 4; ++c)
                        acc[p][c] = fmaf(xk, wq[c], acc[p][c]);
                }
            }
        }

        float* hb = h + (row0 + rBase) * OUT_F + c0;
        #pragma unroll
        for (int p = 0; p < 4; ++p) {
            float4 v;
            v.x = acc[p][0]; v.y = acc[p][1]; v.z = acc[p][2]; v.w = acc[p][3];
            *reinterpret_cast<float4*>(&hb[(size_t)(8 * p) * OUT_F]) = v;
        }
    }
}

// ---------------------------------------------------------------------------
// CSR build: count -> 3-phase multi-block scan -> fill
// ---------------------------------------------------------------------------
__global__ __launch_bounds__(256) void count_edges(const int* __restrict__ edst,
                                                   int* __restrict__ counts,
                                                   int n_edges) {
    const int e = blockIdx.x * 256 + threadIdx.x;
    if (e < n_edges) atomicAdd(&counts[edst[e]], 1);
}

// Phase A: per-block (256-elem) exclusive scan; emit block totals.
__global__ __launch_bounds__(256) void scan_blocks(const int* __restrict__ counts,
                                                   int* __restrict__ offsets,
                                                   int* __restrict__ blockTotals,
                                                   int n) {
    __shared__ int waveTot[4];
    const int tid = threadIdx.x;
    const int lane = tid & 63;
    const int wave = tid >> 6;
    const int i = blockIdx.x * 256 + tid;

    const int v = (i < n) ? counts[i] : 0;

    // Inclusive wave scan.
    int s = v;
    #pragma unroll
    for (int off = 1; off < 64; off <<= 1) {
        const int t = __shfl_up(s, off, 64);
        if (lane >= off) s += t;
    }
    if (lane == 63) waveTot[wave] = s;
    __syncthreads();

    int base = 0;
    #pragma unroll
    for (int w = 0; w < 4; ++w)
        if (w < wave) base += waveTot[w];

    const int incl = s + base;
    if (i < n) offsets[i] = incl - v;               // block-local exclusive
    if (tid == 255) blockTotals[blockIdx.x] = incl; // block total
}

// Phase B: single block scans block totals (nb <= 256); writes exclusive
// bases to blockBases[0..nb-1] and grand total to blockBases[nb].
__global__ __launch_bounds__(256) void scan_totals(const int* __restrict__ blockTotals,
                                                   int* __restrict__ blockBases,
                                                   int nb) {
    __shared__ int part[256];
    const int t = threadIdx.x;
    const int v = (t < nb) ? blockTotals[t] : 0;
    part[t] = v;
    __syncthreads();
    for (int off = 1; off < 256; off <<= 1) {
        const int u = (t >= off) ? part[t - off] : 0;
        __syncthreads();
        part[t] += u;
        __syncthreads();
    }
    if (t < nb) blockBases[t] = part[t] - v;        // exclusive
    if (t == nb - 1) blockBases[nb] = part[t];      // grand total
}

// Phase C: add block base; produce cursor copy and offsets[n].
__global__ __launch_bounds__(256) void add_base(int* __restrict__ offsets,
                                                int* __restrict__ cursor,
                                                const int* __restrict__ blockBases,
                                                int n, int nb) {
    const int i = blockIdx.x * 256 + threadIdx.x;
    if (i < n) {
        const int o = offsets[i] + blockBases[blockIdx.x];
        offsets[i] = o;
        cursor[i] = o;
    }
    if (i == 0) offsets[n] = blockBases[nb];
}

__global__ __launch_bounds__(256) void fill_edges(const int* __restrict__ esrc,
                                                  const int* __restrict__ edst,
                                                  int* __restrict__ cursor,
                                                  int* __restrict__ elist,
                                                  int n_edges) {
    const int e = blockIdx.x * 256 + threadIdx.x;
    if (e < n_edges) {
        const int d = edst[e];
        const int slot = atomicAdd(&cursor[d], 1);
        elist[slot] = esrc[e];
    }
}

// ---------------------------------------------------------------------------
// K5: gather + finalize. One wave per dst, lane = feature.
// ---------------------------------------------------------------------------
__global__ __launch_bounds__(256) void gather_finalize(const float* __restrict__ h,
                                                       const int* __restrict__ offsets,
                                                       const int* __restrict__ elist,
                                                       const float* __restrict__ b,
                                                       float* __restrict__ out,
                                                       int n_dst) {
    const int lane = threadIdx.x & 63;
    const int d = blockIdx.x * 4 + (threadIdx.x >> 6);
    if (d >= n_dst) return;

    const int e0 = offsets[d];
    const int e1 = offsets[d + 1];

    float acc = h[(size_t)d * OUT_F + lane];

    for (int base = e0; base < e1; base += 64) {
        const int cnt = min(64, e1 - base);
        const int sidx = (base + lane < e1) ? elist[base + lane] : 0;
        int j = 0;
        for (; j + 4 <= cnt; j += 4) {
            const int s0 = __shfl(sidx, j);
            const int s1 = __shfl(sidx, j + 1);
            const int s2 = __shfl(sidx, j + 2);
            const int s3 = __shfl(sidx, j + 3);
            const float v0 = h[(size_t)s0 * OUT_F + lane];
            const float v1 = h[(size_t)s1 * OUT_F + lane];
            const float v2 = h[(size_t)s2 * OUT_F + lane];
            const float v3 = h[(size_t)s3 * OUT_F + lane];
            acc += (v0 + v1) + (v2 + v3);
        }
        for (; j < cnt; ++j) {
            const int s = __shfl(sidx, j);
            acc += h[(size_t)s * OUT_F + lane];
        }
    }

    const float deg = (float)(e1 - e0);
    out[(size_t)d * OUT_F + lane] = acc / (deg + 1.0f) + b[lane];
}

static inline size_t align256(size_t v) { return (v + 255) & ~(size_t)255; }

extern "C" void kernel_launch(void* const* d_in, const int* in_sizes, int n_in,
                              void* d_out, int out_size, void* d_ws, size_t ws_size,
                              hipStream_t stream) {
    const float* x    = (const float*)d_in[0];
    const int*   esrc = (const int*)d_in[1];
    const int*   edst = (const int*)d_in[2];
    const float* W    = (const float*)d_in[3];
    const float* b    = (const float*)d_in[4];

    const int n_rows  = in_sizes[0] / IN_F;   // 200000
    const int n_edges = in_sizes[1];          // 800000
    const int n_dst   = out_size / OUT_F;     // 50000
    float* out = (float*)d_out;

    const int nScanBlocks = (n_dst + 255) / 256;            // 196

    // Workspace layout
    const size_t hBytes  = (size_t)n_rows * OUT_F * sizeof(float);   // 51.2 MB
    const size_t cntOff  = align256(hBytes);
    const size_t offOff  = align256(cntOff + (size_t)n_dst * 4);
    const size_t curOff  = align256(offOff + ((size_t)n_dst + 1) * 4);
    const size_t btOff   = align256(curOff + (size_t)n_dst * 4);
    const size_t bbOff   = align256(btOff + ((size_t)nScanBlocks + 1) * 4);
    const size_t elOff   = align256(bbOff + ((size_t)nScanBlocks + 1) * 4);
    const size_t needed  = elOff + (size_t)n_edges * 4;

    float* h = (float*)d_ws;

    // K1: GEMM (persistent, 2 blocks/CU).
    const int nTiles = n_rows / 64;           // 3125
    gemm_xw<<<512, 256, 0, stream>>>(x, W, h, nTiles);

    if (ws_size >= needed) {
        int* counts      = (int*)((char*)d_ws + cntOff);
        int* offsets     = (int*)((char*)d_ws + offOff);
        int* cursor      = (int*)((char*)d_ws + curOff);
        int* blockTotals = (int*)((char*)d_ws + btOff);
        int* blockBases  = (int*)((char*)d_ws + bbOff);
        int* elist       = (int*)((char*)d_ws + elOff);

        hipMemsetAsync(counts, 0, (size_t)n_dst * 4, stream);

        const int eBlocks = (n_edges + 255) / 256;
        count_edges<<<eBlocks, 256, 0, stream>>>(edst, counts, n_edges);
        scan_blocks<<<nScanBlocks, 256, 0, stream>>>(counts, offsets, blockTotals, n_dst);
        scan_totals<<<1, 256, 0, stream>>>(blockTotals, blockBases, nScanBlocks);
        add_base<<<nScanBlocks, 256, 0, stream>>>(offsets, cursor, blockBases, n_dst, nScanBlocks);
        fill_edges<<<eBlocks, 256, 0, stream>>>(esrc, edst, cursor, elist, n_edges);

        const int gBlocks = (n_dst + 3) / 4;
        gather_finalize<<<gBlocks, 256, 0, stream>>>(h, offsets, elist, b, out, n_dst);
    } else {
        // Should not happen (needed ~55 MB); emergency fallback: zero output.
        hipMemsetAsync(out, 0, (size_t)out_size * sizeof(float), stream);
    }
}